// Round 5
// baseline (2603.632 us; speedup 1.0000x reference)
//
#include <hip/hip_runtime.h>
#include <hip/hip_bf16.h>

#define Tn 64
#define NB 16
#define NTH 1024

typedef unsigned int u32;
typedef _Float16 h2 __attribute__((ext_vector_type(2)));
typedef __fp16 fp16x2 __attribute__((ext_vector_type(2)));
typedef short s16x8 __attribute__((ext_vector_type(8)));
typedef float f32x4 __attribute__((ext_vector_type(4)));

#define MFMA16(a, b, c) __builtin_amdgcn_mfma_f32_16x16x32_bf16(a, b, c, 0, 0, 0)

__device__ __forceinline__ h2 as_h2(u32 u) { union { u32 u; h2 h; } c; c.u = u; return c.h; }

__device__ __forceinline__ float dot2h(u32 a, u32 w, float acc) {
  return __builtin_amdgcn_fdot2(as_h2(a), as_h2(w), acc, false);
}

__device__ __forceinline__ u32 pkh(float a, float b) {
  union { u32 u; fp16x2 h; } c;
  c.h = __builtin_amdgcn_cvt_pkrtz(a, b);
  return c.u;
}

__device__ __forceinline__ unsigned short bfq(float x) {
  u32 u = __float_as_uint(x);
  return (unsigned short)((u + 0x7fffu + ((u >> 16) & 1)) >> 16);
}

__device__ __forceinline__ u32 pack2bf(float a, float b) {
  u32 ua = __float_as_uint(a), ub = __float_as_uint(b);
  ua = (ua + 0x7fffu + ((ua >> 16) & 1)) >> 16;
  ub = (ub + 0x7fffu + ((ub >> 16) & 1)) >> 16;
  return (ua & 0xffffu) | (ub << 16);
}

#define FEXP(x) __builtin_amdgcn_exp2f(x)
#define CE 2.885390081777927f /* 2*log2(e) */

__device__ __forceinline__ float fast_rcp(float x) { return __builtin_amdgcn_rcpf(x); }
__device__ __forceinline__ float rcp1(float e) { return __builtin_amdgcn_rcpf(1.f + e); }
__device__ __forceinline__ float fast_tanh(float x) {
  float e = __expf(2.f * x);
  return 1.f - 2.f * fast_rcp(1.f + e);
}
__device__ __forceinline__ float fast_sig(float x) {
  return fast_rcp(1.f + __expf(-x));
}

// ---------------- weight pre-pack ----------------
// ws layout (bytes):
//   WdP   bf16 [kk<8][w<8][lane<64][e<8]      @ 0        (65536)
//   WhhP  bf16 [kk<4][nt<32][lane<64][e<8]    @ 65536    (131072)
//   WdecP bf16 [t<65][kk<4][w<8][lane][e<8]   @ 196608   (2129920)
//   UdP   u32-f16pair [k2<64][m<128]          @ 2326528  (32768)
//   wtP   u32-f16pair [k2<64]                 @ 2359296  (256)
//   WyP2  u32-f16pair [k<256][j<64]           @ 2359552  (65536)
__global__ void pack_weights(const float* __restrict__ W_d_w,
                             const float* __restrict__ W_hh,
                             const float* __restrict__ W_dec_w,
                             const float* __restrict__ W_y_w,
                             const float* __restrict__ U_d_w,
                             const float* __restrict__ w_tilda_w,
                             short* __restrict__ WdP, short* __restrict__ WhhP,
                             short* __restrict__ WdecP, u32* __restrict__ UdP,
                             u32* __restrict__ wtP, u32* __restrict__ WyP2) {
  const int i0 = blockIdx.x * blockDim.x + threadIdx.x;
  const int stride = gridDim.x * blockDim.x;
  for (int i = i0; i < 32768; i += stride) {  // WdP
    int e = i & 7, lane = (i >> 3) & 63, w = (i >> 9) & 7, kk = i >> 12;
    int n = w * 16 + (lane & 15), k = kk * 32 + (lane >> 4) * 8 + e;
    WdP[i] = (short)bfq(W_d_w[n * 256 + k]);
  }
  for (int i = i0; i < 65536; i += stride) {  // WhhP
    int e = i & 7, lane = (i >> 3) & 63, nt = (i >> 9) & 31, kk = i >> 14;
    int n = nt * 16 + (lane & 15), k = kk * 32 + (lane >> 4) * 8 + e;
    WhhP[i] = (short)bfq(W_hh[n * 128 + k]);
  }
  for (int i = i0; i < 1064960; i += stride) {  // WdecP (blocks 0..64)
    int e = i & 7, lane = (i >> 3) & 63, w = (i >> 9) & 7, kk = (i >> 12) & 3, tt = i >> 14;
    int n = w * 16 + (lane & 15), k = kk * 32 + (lane >> 4) * 8 + e;
    WdecP[i] = (short)bfq(W_dec_w[n * 8320 + tt * 128 + k]);
  }
  for (int i = i0; i < 8192; i += stride) {  // UdP
    int m = i & 127, k2 = i >> 7;
    UdP[i] = pkh(U_d_w[m * 128 + 2 * k2], U_d_w[m * 128 + 2 * k2 + 1]);
  }
  for (int i = i0; i < 64; i += stride)  // wtP
    wtP[i] = pkh(w_tilda_w[2 * i], w_tilda_w[2 * i + 1]);
  for (int i = i0; i < 16384; i += stride) {  // WyP2
    int jj = i & 63, k = i >> 6;
    WyP2[i] = pkh(W_y_w[(2 * jj) * 256 + k], W_y_w[(2 * jj + 1) * 256 + k]);
  }
}

// ---------------- fused scan ----------------
// LDS (bytes):
//   cat   u32 [16][132]   @ 0      (8448)
//   x1c   f32 [16][132]   @ 8448   (8448)
//   gates f32 [16][516]   @ 16896  (33024)
//   va2   f32 [128]       @ 49920  (512)
//   wih_s f32 [512]       @ 50432  (2048)
//   beta  f32 [16][64]    @ 52480  (4096)
//   cat2  f32 [16][256]   @ 56576  (16384)
#define LDS_BYTES 72960

__global__ __launch_bounds__(NTH, 4) void fused_main(
    const float* __restrict__ enc, const float* __restrict__ y,
    const float* __restrict__ W_d_b, const float* __restrict__ v_d_w,
    const float* __restrict__ w_tilda_w, const float* __restrict__ w_tilda_b,
    const float* __restrict__ W_ih, const float* __restrict__ b_ih,
    const float* __restrict__ b_hh, const float* __restrict__ W_dec_b,
    const float* __restrict__ W_y_b, const float* __restrict__ v_y_w,
    const float* __restrict__ v_y_b,
    const short* __restrict__ WdP, const short* __restrict__ WhhP,
    const short* __restrict__ WdecP, const uint4* __restrict__ UdP4,
    const u32* __restrict__ wtP, const u32* __restrict__ WyP2,
    float* __restrict__ out) {
  extern __shared__ char lds[];
  u32* cat_u = (u32*)lds;
  float* x1c = (float*)(lds + 8448);
  float* gates = (float*)(lds + 16896);
  float* va2 = (float*)(lds + 49920);
  float* wih_s = (float*)(lds + 50432);
  float* beta_s = (float*)(lds + 52480);
  float* cat2 = (float*)(lds + 56576);

  const int tid = threadIdx.x;
  const int lane = tid & 63;
  const int wv = tid >> 6;  // 0..15 == bb
  const int b = blockIdx.x * NB + wv;
  const int j = lane;

  for (int i = tid; i < 2112; i += NTH) cat_u[i] = 0u;
  if (wv == 0) {
    va2[lane] = 2.f * v_d_w[lane];
    va2[64 + lane] = 2.f * v_d_w[64 + lane];
  }
  for (int i = tid; i < 512; i += NTH) wih_s[i] = W_ih[i];

  // ---- phase 0: y1 into 64 VGPRs (f16 pairs), chunked to avoid spills ----
  const float* enc_row = enc + ((size_t)b * 64 + lane) * 128;
  float ew = 0.f;
  u32 y1p[64];
#pragma unroll
  for (int ch = 0; ch < 4; ++ch) {
    float acc[32];
#pragma unroll
    for (int i = 0; i < 32; ++i) acc[i] = 0.f;
    for (int k2 = 0; k2 < 64; ++k2) {
      float2 ev = *(const float2*)(enc_row + 2 * k2);
      u32 ep = pkh(ev.x, ev.y);
      if (ch == 0) ew = dot2h(ep, wtP[k2], ew);
#pragma unroll
      for (int mm = 0; mm < 8; ++mm) {
        uint4 uv = UdP4[k2 * 32 + ch * 8 + mm];
        acc[mm * 4 + 0] = dot2h(ep, uv.x, acc[mm * 4 + 0]);
        acc[mm * 4 + 1] = dot2h(ep, uv.y, acc[mm * 4 + 1]);
        acc[mm * 4 + 2] = dot2h(ep, uv.z, acc[mm * 4 + 2]);
        acc[mm * 4 + 3] = dot2h(ep, uv.w, acc[mm * 4 + 3]);
      }
    }
#pragma unroll
    for (int i = 0; i < 16; ++i) y1p[ch * 16 + i] = pkh(acc[2 * i], acc[2 * i + 1]);
  }

  const float wt_y = w_tilda_w[128];
  const float wt_b0 = w_tilda_b[0];
  float sv = v_d_w[lane] + v_d_w[64 + lane];
#pragma unroll
  for (int off = 32; off; off >>= 1) sv += __shfl_xor(sv, off, 64);

  const int ccol = lane & 15;
  const int crow = (lane >> 4) * 4;
  const int arow = ccol * 132 + (lane >> 4) * 4;  // u32 index of A-frag
  const float wdb_n = W_d_b[(wv & 7) * 16 + ccol];
  const float dfb_n = W_dec_b[(wv & 7) * 16 + ccol];
  const float bini0 = b_ih[wv * 32 + ccol] + b_hh[wv * 32 + ccol];
  const float bini1 = b_ih[wv * 32 + 16 + ccol] + b_hh[wv * 32 + 16 + ccol];
  f32x4 dfacc = {dfb_n, dfb_n, dfb_n, dfb_n};
  float s0 = 0.f, s1 = 0.f, beta_sv = 0.f;

  __syncthreads();

#pragma unroll 1
  for (int t = 0; t < Tn; ++t) {
    // ---- phase A: GEMMs on the matrix pipe ----
    if (wv < 8) {
      f32x4 c1 = {wdb_n, wdb_n, wdb_n, wdb_n};
#pragma unroll
      for (int kk = 0; kk < 8; ++kk) {
        s16x8 a = *(const s16x8*)(cat_u + arow + kk * 16);
        s16x8 bf = *(const s16x8*)(WdP + (((kk * 8 + wv) * 64 + lane) * 8));
        c1 = MFMA16(a, bf, c1);
      }
#pragma unroll
      for (int r = 0; r < 4; ++r)
        x1c[(crow + r) * 132 + wv * 16 + ccol] = c1[r] * CE;
    } else {
      const int w8 = wv - 8;
#pragma unroll
      for (int kk = 0; kk < 4; ++kk) {
        s16x8 a = *(const s16x8*)(cat_u + arow + kk * 16);
        s16x8 bf = *(const s16x8*)(WdecP + ((((t * 4 + kk) * 8 + w8) * 64 + lane) * 8));
        dfacc = MFMA16(a, bf, dfacc);
      }
    }
#pragma unroll
    for (int it = 0; it < 2; ++it) {
      const float bini = it ? bini1 : bini0;
      f32x4 c2 = {bini, bini, bini, bini};
      const int nt = wv * 2 + it;
#pragma unroll
      for (int kk = 0; kk < 4; ++kk) {
        s16x8 a = *(const s16x8*)(cat_u + arow + kk * 16);
        s16x8 bf = *(const s16x8*)(WhhP + (((kk * 32 + nt) * 64 + lane) * 8));
        c2 = MFMA16(a, bf, c2);
      }
#pragma unroll
      for (int r = 0; r < 4; ++r)
        gates[(crow + r) * 516 + nt * 16 + ccol] = c2[r];
    }
    __syncthreads();

    // ---- phase B: logits, softmax, LSTM pointwise (wave = batch row) ----
    float q0 = 0.f, q1 = 0.f, q2 = 0.f, q3 = 0.f;
#pragma unroll
    for (int i8 = 0; i8 < 16; ++i8) {
      float4 xa = *(const float4*)(x1c + wv * 132 + i8 * 8);
      float4 xb = *(const float4*)(x1c + wv * 132 + i8 * 8 + 4);
      float4 va = *(const float4*)(va2 + i8 * 8);
      float4 vb = *(const float4*)(va2 + i8 * 8 + 4);
      h2 p;
      p = as_h2(y1p[i8 * 4 + 0]);
      q0 = fmaf(va.x, rcp1(FEXP(fmaf((float)p.x, CE, xa.x))), q0);
      q1 = fmaf(va.y, rcp1(FEXP(fmaf((float)p.y, CE, xa.y))), q1);
      p = as_h2(y1p[i8 * 4 + 1]);
      q2 = fmaf(va.z, rcp1(FEXP(fmaf((float)p.x, CE, xa.z))), q2);
      q3 = fmaf(va.w, rcp1(FEXP(fmaf((float)p.y, CE, xa.w))), q3);
      p = as_h2(y1p[i8 * 4 + 2]);
      q0 = fmaf(vb.x, rcp1(FEXP(fmaf((float)p.x, CE, xb.x))), q0);
      q1 = fmaf(vb.y, rcp1(FEXP(fmaf((float)p.y, CE, xb.y))), q1);
      p = as_h2(y1p[i8 * 4 + 3]);
      q2 = fmaf(vb.z, rcp1(FEXP(fmaf((float)p.x, CE, xb.z))), q2);
      q3 = fmaf(vb.w, rcp1(FEXP(fmaf((float)p.y, CE, xb.w))), q3);
    }
    float lg = sv - (q0 + q1 + q2 + q3);  // |lg| bounded ~15: skip max pass
    float pexp = __expf(lg);
    float smv = pexp, yt = pexp * ew;
#pragma unroll
    for (int off = 32; off; off >>= 1) {
      smv += __shfl_xor(smv, off, 64);
      yt += __shfl_xor(yt, off, 64);
    }
    float rs = fast_rcp(smv);
    beta_sv = pexp * rs;
    float ytil = yt * rs + y[(size_t)b * 64 + t] * wt_y + wt_b0;

    float2 gi = *(const float2*)(gates + wv * 516 + 2 * j);
    float2 gf = *(const float2*)(gates + wv * 516 + 128 + 2 * j);
    float2 gg = *(const float2*)(gates + wv * 516 + 256 + 2 * j);
    float2 go = *(const float2*)(gates + wv * 516 + 384 + 2 * j);
    float2 wi0 = *(const float2*)(wih_s + 2 * j);
    float2 wi1 = *(const float2*)(wih_s + 128 + 2 * j);
    float2 wi2 = *(const float2*)(wih_s + 256 + 2 * j);
    float2 wi3 = *(const float2*)(wih_s + 384 + 2 * j);
    float i0 = fast_sig(gi.x + ytil * wi0.x);
    float i1 = fast_sig(gi.y + ytil * wi0.y);
    float f0 = fast_sig(gf.x + ytil * wi1.x);
    float f1 = fast_sig(gf.y + ytil * wi1.y);
    float g0 = fast_tanh(gg.x + ytil * wi2.x);
    float g1 = fast_tanh(gg.y + ytil * wi2.y);
    float o0 = fast_sig(go.x + ytil * wi3.x);
    float o1 = fast_sig(go.y + ytil * wi3.y);
    s0 = f0 * s0 + i0 * g0;
    s1 = f1 * s1 + i1 * g1;
    float d0 = o0 * fast_tanh(s0);
    float d1 = o1 * fast_tanh(s1);
    cat_u[wv * 132 + j] = pack2bf(d0, d1);
    cat_u[wv * 132 + 64 + j] = pack2bf(s0, s1);
    __syncthreads();
  }

  // ---- epilogue: d_64 * Wdec block 64, write d_fin ----
  if (wv >= 8) {
    const int w8 = wv - 8;
#pragma unroll
    for (int kk = 0; kk < 4; ++kk) {
      s16x8 a = *(const s16x8*)(cat_u + arow + kk * 16);
      s16x8 bf = *(const s16x8*)(WdecP + ((((64 * 4 + kk) * 8 + w8) * 64 + lane) * 8));
      dfacc = MFMA16(a, bf, dfacc);
    }
#pragma unroll
    for (int r = 0; r < 4; ++r)
      cat2[(crow + r) * 256 + w8 * 16 + ccol] = dfacc[r];
  }
  beta_s[wv * 64 + lane] = beta_sv;
  __syncthreads();

  // ---- c_T and final head (per wave) ----
  float c0 = 0.f, c1v = 0.f;
#pragma unroll 2
  for (int it = 0; it < 16; ++it) {
    float4 bv = *(const float4*)(beta_s + wv * 64 + it * 4);
    float2 e0 = *(const float2*)(enc + ((size_t)b * 64 + it * 4 + 0) * 128 + 2 * j);
    float2 e1 = *(const float2*)(enc + ((size_t)b * 64 + it * 4 + 1) * 128 + 2 * j);
    float2 e2 = *(const float2*)(enc + ((size_t)b * 64 + it * 4 + 2) * 128 + 2 * j);
    float2 e3 = *(const float2*)(enc + ((size_t)b * 64 + it * 4 + 3) * 128 + 2 * j);
    c0 = fmaf(bv.x, e0.x, c0); c1v = fmaf(bv.x, e0.y, c1v);
    c0 = fmaf(bv.y, e1.x, c0); c1v = fmaf(bv.y, e1.y, c1v);
    c0 = fmaf(bv.z, e2.x, c0); c1v = fmaf(bv.z, e2.y, c1v);
    c0 = fmaf(bv.w, e3.x, c0); c1v = fmaf(bv.w, e3.y, c1v);
  }
  *(float2*)(cat2 + wv * 256 + 128 + 2 * j) = make_float2(c0, c1v);

  float2 hb = *(const float2*)(W_y_b + 2 * j);
  float h0 = hb.x, h1 = hb.y;
  __syncthreads();
#pragma unroll 4
  for (int it = 0; it < 64; ++it) {
    float4 cv = *(const float4*)(cat2 + wv * 256 + it * 4);
    u32 w0 = WyP2[(it * 4 + 0) * 64 + j];
    u32 w1 = WyP2[(it * 4 + 1) * 64 + j];
    u32 w2 = WyP2[(it * 4 + 2) * 64 + j];
    u32 w3 = WyP2[(it * 4 + 3) * 64 + j];
    h2 p0 = as_h2(w0), p1 = as_h2(w1), p2 = as_h2(w2), p3 = as_h2(w3);
    h0 = fmaf(cv.x, (float)p0.x, h0); h1 = fmaf(cv.x, (float)p0.y, h1);
    h0 = fmaf(cv.y, (float)p1.x, h0); h1 = fmaf(cv.y, (float)p1.y, h1);
    h0 = fmaf(cv.z, (float)p2.x, h0); h1 = fmaf(cv.z, (float)p2.y, h1);
    h0 = fmaf(cv.w, (float)p3.x, h0); h1 = fmaf(cv.w, (float)p3.y, h1);
  }
  float2 vy = *(const float2*)(v_y_w + 2 * j);
  float r = h0 * vy.x + h1 * vy.y;
#pragma unroll
  for (int off = 32; off; off >>= 1) r += __shfl_xor(r, off, 64);
  if (lane == 0) out[b] = r + v_y_b[0];
}

extern "C" void kernel_launch(void* const* d_in, const int* in_sizes, int n_in,
                              void* d_out, int out_size, void* d_ws, size_t ws_size,
                              hipStream_t stream) {
  const float* enc = (const float*)d_in[0];
  const float* y = (const float*)d_in[1];
  const float* W_d_w = (const float*)d_in[2];
  const float* W_d_b = (const float*)d_in[3];
  const float* U_d_w = (const float*)d_in[4];
  const float* v_d_w = (const float*)d_in[5];
  const float* w_tilda_w = (const float*)d_in[6];
  const float* w_tilda_b = (const float*)d_in[7];
  const float* W_ih = (const float*)d_in[8];
  const float* b_ih = (const float*)d_in[9];
  const float* W_hh = (const float*)d_in[10];
  const float* b_hh = (const float*)d_in[11];
  const float* W_dec_w = (const float*)d_in[12];
  const float* W_dec_b = (const float*)d_in[13];
  const float* W_y_w = (const float*)d_in[14];
  const float* W_y_b = (const float*)d_in[15];
  const float* v_y_w = (const float*)d_in[16];
  const float* v_y_b = (const float*)d_in[17];

  char* ws = (char*)d_ws;
  short* WdP = (short*)(ws + 0);
  short* WhhP = (short*)(ws + 65536);
  short* WdecP = (short*)(ws + 196608);
  u32* UdP = (u32*)(ws + 2326528);
  u32* wtP = (u32*)(ws + 2359296);
  u32* WyP2 = (u32*)(ws + 2359552);

  pack_weights<<<512, 256, 0, stream>>>(W_d_w, W_hh, W_dec_w, W_y_w, U_d_w,
                                        w_tilda_w, WdP, WhhP, WdecP, UdP, wtP, WyP2);
  fused_main<<<4096 / NB, NTH, LDS_BYTES, stream>>>(
      enc, y, W_d_b, v_d_w, w_tilda_w, w_tilda_b, W_ih, b_ih, b_hh, W_dec_b,
      W_y_b, v_y_w, v_y_b, WdP, WhhP, WdecP, (const uint4*)UdP, wtP, WyP2,
      (float*)d_out);
}

// Round 6
// 1284.357 us; speedup vs baseline: 2.0272x; 2.0272x over previous
//
#include <hip/hip_runtime.h>
#include <hip/hip_bf16.h>

#define Tn 64
#define NB 16
#define NTH 1024

typedef unsigned int u32;
typedef _Float16 h2 __attribute__((ext_vector_type(2)));
typedef __fp16 fp16x2 __attribute__((ext_vector_type(2)));
typedef short s16x8 __attribute__((ext_vector_type(8)));
typedef float f32x4 __attribute__((ext_vector_type(4)));

#define MFMA16(a, b, c) __builtin_amdgcn_mfma_f32_16x16x32_bf16(a, b, c, 0, 0, 0)

__device__ __forceinline__ h2 as_h2(u32 u) { union { u32 u; h2 h; } c; c.u = u; return c.h; }

__device__ __forceinline__ float dot2h(u32 a, u32 w, float acc) {
  return __builtin_amdgcn_fdot2(as_h2(a), as_h2(w), acc, false);
}

__device__ __forceinline__ u32 pkh(float a, float b) {
  union { u32 u; fp16x2 h; } c;
  c.h = __builtin_amdgcn_cvt_pkrtz(a, b);
  return c.u;
}

__device__ __forceinline__ unsigned short bfq(float x) {
  u32 u = __float_as_uint(x);
  return (unsigned short)((u + 0x7fffu + ((u >> 16) & 1)) >> 16);
}

__device__ __forceinline__ u32 pack2bf(float a, float b) {
  u32 ua = __float_as_uint(a), ub = __float_as_uint(b);
  ua = (ua + 0x7fffu + ((ua >> 16) & 1)) >> 16;
  ub = (ub + 0x7fffu + ((ub >> 16) & 1)) >> 16;
  return (ua & 0xffffu) | (ub << 16);
}

#define FEXP(x) __builtin_amdgcn_exp2f(x)
#define CE 2.885390081777927f /* 2*log2(e) */

__device__ __forceinline__ float fast_rcp(float x) { return __builtin_amdgcn_rcpf(x); }
__device__ __forceinline__ float rcp1(float e) { return __builtin_amdgcn_rcpf(1.f + e); }
__device__ __forceinline__ float fast_tanh(float x) {
  float e = __expf(2.f * x);
  return 1.f - 2.f * fast_rcp(1.f + e);
}
__device__ __forceinline__ float fast_sig(float x) {
  return fast_rcp(1.f + __expf(-x));
}

// ---------------- weight pre-pack ----------------
// ws layout (bytes):
//   WdP   bf16 [kk<8][w<8][lane<64][e<8]      @ 0        (65536)
//   WhhP  bf16 [kk<4][nt<32][lane<64][e<8]    @ 65536    (131072)
//   WdecP bf16 [t<65][kk<4][w<8][lane][e<8]   @ 196608   (2129920)
//   UdP   u32-f16pair [k2<64][m<128]          @ 2326528  (32768)
//   wtP   u32-f16pair [k2<64]                 @ 2359296  (256)
//   WyP2  u32-f16pair [k<256][j<64]           @ 2359552  (65536)
__global__ void pack_weights(const float* __restrict__ W_d_w,
                             const float* __restrict__ W_hh,
                             const float* __restrict__ W_dec_w,
                             const float* __restrict__ W_y_w,
                             const float* __restrict__ U_d_w,
                             const float* __restrict__ w_tilda_w,
                             short* __restrict__ WdP, short* __restrict__ WhhP,
                             short* __restrict__ WdecP, u32* __restrict__ UdP,
                             u32* __restrict__ wtP, u32* __restrict__ WyP2) {
  const int i0 = blockIdx.x * blockDim.x + threadIdx.x;
  const int stride = gridDim.x * blockDim.x;
  for (int i = i0; i < 32768; i += stride) {  // WdP
    int e = i & 7, lane = (i >> 3) & 63, w = (i >> 9) & 7, kk = i >> 12;
    int n = w * 16 + (lane & 15), k = kk * 32 + (lane >> 4) * 8 + e;
    WdP[i] = (short)bfq(W_d_w[n * 256 + k]);
  }
  for (int i = i0; i < 65536; i += stride) {  // WhhP
    int e = i & 7, lane = (i >> 3) & 63, nt = (i >> 9) & 31, kk = i >> 14;
    int n = nt * 16 + (lane & 15), k = kk * 32 + (lane >> 4) * 8 + e;
    WhhP[i] = (short)bfq(W_hh[n * 128 + k]);
  }
  for (int i = i0; i < 1064960; i += stride) {  // WdecP (blocks 0..64)
    int e = i & 7, lane = (i >> 3) & 63, w = (i >> 9) & 7, kk = (i >> 12) & 3, tt = i >> 14;
    int n = w * 16 + (lane & 15), k = kk * 32 + (lane >> 4) * 8 + e;
    WdecP[i] = (short)bfq(W_dec_w[n * 8320 + tt * 128 + k]);
  }
  for (int i = i0; i < 8192; i += stride) {  // UdP
    int m = i & 127, k2 = i >> 7;
    UdP[i] = pkh(U_d_w[m * 128 + 2 * k2], U_d_w[m * 128 + 2 * k2 + 1]);
  }
  for (int i = i0; i < 64; i += stride)  // wtP
    wtP[i] = pkh(w_tilda_w[2 * i], w_tilda_w[2 * i + 1]);
  for (int i = i0; i < 16384; i += stride) {  // WyP2
    int jj = i & 63, k = i >> 6;
    WyP2[i] = pkh(W_y_w[(2 * jj) * 256 + k], W_y_w[(2 * jj + 1) * 256 + k]);
  }
}

// ---------------- fused scan ----------------
// LDS (bytes):
//   cat   u32 [16][132]   @ 0      (8448)
//   x1c   f32 [16][132]   @ 8448   (8448)
//   gates f32 [16][516]   @ 16896  (33024)
//   va2   f32 [128]       @ 49920  (512)
//   wih_s f32 [512]       @ 50432  (2048)
//   beta  f32 [16][64]    @ 52480  (4096)
//   cat2  f32 [16][256]   @ 56576  (16384)
#define LDS_BYTES 72960

__global__ __launch_bounds__(NTH)
__attribute__((amdgpu_waves_per_eu(4, 4)))
void fused_main(
    const float* __restrict__ enc, const float* __restrict__ y,
    const float* __restrict__ W_d_b, const float* __restrict__ v_d_w,
    const float* __restrict__ w_tilda_w, const float* __restrict__ w_tilda_b,
    const float* __restrict__ W_ih, const float* __restrict__ b_ih,
    const float* __restrict__ b_hh, const float* __restrict__ W_dec_b,
    const float* __restrict__ W_y_b, const float* __restrict__ v_y_w,
    const float* __restrict__ v_y_b,
    const short* __restrict__ WdP, const short* __restrict__ WhhP,
    const short* __restrict__ WdecP, const uint4* __restrict__ UdP4,
    const u32* __restrict__ wtP, const u32* __restrict__ WyP2,
    float* __restrict__ out) {
  extern __shared__ char lds[];
  u32* cat_u = (u32*)lds;
  float* x1c = (float*)(lds + 8448);
  float* gates = (float*)(lds + 16896);
  float* va2 = (float*)(lds + 49920);
  float* wih_s = (float*)(lds + 50432);
  float* beta_s = (float*)(lds + 52480);
  float* cat2 = (float*)(lds + 56576);

  const int tid = threadIdx.x;
  const int lane = tid & 63;
  const int wv = tid >> 6;  // 0..15 == bb
  const int b = blockIdx.x * NB + wv;
  const int j = lane;

  for (int i = tid; i < 2112; i += NTH) cat_u[i] = 0u;
  if (wv == 0) {
    va2[lane] = 2.f * v_d_w[lane];
    va2[64 + lane] = 2.f * v_d_w[64 + lane];
  }
  for (int i = tid; i < 512; i += NTH) wih_s[i] = W_ih[i];

  // ---- phase 0: y1 into 64 VGPRs (f16 pairs), chunked to bound peak regs ----
  const float* enc_row = enc + ((size_t)b * 64 + lane) * 128;
  float ew = 0.f;
  u32 y1p[64];
#pragma unroll
  for (int ch = 0; ch < 4; ++ch) {
    float acc[32];
#pragma unroll
    for (int i = 0; i < 32; ++i) acc[i] = 0.f;
    for (int k2 = 0; k2 < 64; ++k2) {
      float2 ev = *(const float2*)(enc_row + 2 * k2);
      u32 ep = pkh(ev.x, ev.y);
      if (ch == 0) ew = dot2h(ep, wtP[k2], ew);
#pragma unroll
      for (int mm = 0; mm < 8; ++mm) {
        uint4 uv = UdP4[k2 * 32 + ch * 8 + mm];
        acc[mm * 4 + 0] = dot2h(ep, uv.x, acc[mm * 4 + 0]);
        acc[mm * 4 + 1] = dot2h(ep, uv.y, acc[mm * 4 + 1]);
        acc[mm * 4 + 2] = dot2h(ep, uv.z, acc[mm * 4 + 2]);
        acc[mm * 4 + 3] = dot2h(ep, uv.w, acc[mm * 4 + 3]);
      }
    }
#pragma unroll
    for (int i = 0; i < 16; ++i) y1p[ch * 16 + i] = pkh(acc[2 * i], acc[2 * i + 1]);
  }

  const float wt_y = w_tilda_w[128];
  const float wt_b0 = w_tilda_b[0];
  float sv = v_d_w[lane] + v_d_w[64 + lane];
#pragma unroll
  for (int off = 32; off; off >>= 1) sv += __shfl_xor(sv, off, 64);

  const int ccol = lane & 15;
  const int crow = (lane >> 4) * 4;
  const int arow = ccol * 132 + (lane >> 4) * 4;  // u32 index of A-frag
  const float wdb_n = W_d_b[(wv & 7) * 16 + ccol];
  const float dfb_n = W_dec_b[(wv & 7) * 16 + ccol];
  const float bini0 = b_ih[wv * 32 + ccol] + b_hh[wv * 32 + ccol];
  const float bini1 = b_ih[wv * 32 + 16 + ccol] + b_hh[wv * 32 + 16 + ccol];
  f32x4 dfacc = {dfb_n, dfb_n, dfb_n, dfb_n};
  float s0 = 0.f, s1 = 0.f, beta_sv = 0.f;

  __syncthreads();

#pragma unroll 1
  for (int t = 0; t < Tn; ++t) {
    // ---- phase A: GEMMs on the matrix pipe ----
    if (wv < 8) {
      f32x4 c1 = {wdb_n, wdb_n, wdb_n, wdb_n};
#pragma unroll
      for (int kk = 0; kk < 8; ++kk) {
        s16x8 a = *(const s16x8*)(cat_u + arow + kk * 16);
        s16x8 bf = *(const s16x8*)(WdP + (((kk * 8 + wv) * 64 + lane) * 8));
        c1 = MFMA16(a, bf, c1);
      }
#pragma unroll
      for (int r = 0; r < 4; ++r)
        x1c[(crow + r) * 132 + wv * 16 + ccol] = c1[r] * CE;
    } else {
      const int w8 = wv - 8;
#pragma unroll
      for (int kk = 0; kk < 4; ++kk) {
        s16x8 a = *(const s16x8*)(cat_u + arow + kk * 16);
        s16x8 bf = *(const s16x8*)(WdecP + ((((t * 4 + kk) * 8 + w8) * 64 + lane) * 8));
        dfacc = MFMA16(a, bf, dfacc);
      }
    }
#pragma unroll
    for (int it = 0; it < 2; ++it) {
      const float bini = it ? bini1 : bini0;
      f32x4 c2 = {bini, bini, bini, bini};
      const int nt = wv * 2 + it;
#pragma unroll
      for (int kk = 0; kk < 4; ++kk) {
        s16x8 a = *(const s16x8*)(cat_u + arow + kk * 16);
        s16x8 bf = *(const s16x8*)(WhhP + (((kk * 32 + nt) * 64 + lane) * 8));
        c2 = MFMA16(a, bf, c2);
      }
#pragma unroll
      for (int r = 0; r < 4; ++r)
        gates[(crow + r) * 516 + nt * 16 + ccol] = c2[r];
    }
    __syncthreads();

    // ---- phase B: logits, softmax, LSTM pointwise (wave = batch row) ----
    float q0 = 0.f, q1 = 0.f, q2 = 0.f, q3 = 0.f;
#pragma unroll 4
    for (int i8 = 0; i8 < 16; ++i8) {
      float4 xa = *(const float4*)(x1c + wv * 132 + i8 * 8);
      float4 xb = *(const float4*)(x1c + wv * 132 + i8 * 8 + 4);
      float4 va = *(const float4*)(va2 + i8 * 8);
      float4 vb = *(const float4*)(va2 + i8 * 8 + 4);
      h2 p;
      p = as_h2(y1p[i8 * 4 + 0]);
      q0 = fmaf(va.x, rcp1(FEXP(fmaf((float)p.x, CE, xa.x))), q0);
      q1 = fmaf(va.y, rcp1(FEXP(fmaf((float)p.y, CE, xa.y))), q1);
      p = as_h2(y1p[i8 * 4 + 1]);
      q2 = fmaf(va.z, rcp1(FEXP(fmaf((float)p.x, CE, xa.z))), q2);
      q3 = fmaf(va.w, rcp1(FEXP(fmaf((float)p.y, CE, xa.w))), q3);
      p = as_h2(y1p[i8 * 4 + 2]);
      q0 = fmaf(vb.x, rcp1(FEXP(fmaf((float)p.x, CE, xb.x))), q0);
      q1 = fmaf(vb.y, rcp1(FEXP(fmaf((float)p.y, CE, xb.y))), q1);
      p = as_h2(y1p[i8 * 4 + 3]);
      q2 = fmaf(vb.z, rcp1(FEXP(fmaf((float)p.x, CE, xb.z))), q2);
      q3 = fmaf(vb.w, rcp1(FEXP(fmaf((float)p.y, CE, xb.w))), q3);
    }
    float lg = sv - (q0 + q1 + q2 + q3);  // |lg| bounded ~15: skip max pass
    float pexp = __expf(lg);
    float smv = pexp, yt = pexp * ew;
#pragma unroll
    for (int off = 32; off; off >>= 1) {
      smv += __shfl_xor(smv, off, 64);
      yt += __shfl_xor(yt, off, 64);
    }
    float rs = fast_rcp(smv);
    beta_sv = pexp * rs;
    float ytil = yt * rs + y[(size_t)b * 64 + t] * wt_y + wt_b0;

    float2 gi = *(const float2*)(gates + wv * 516 + 2 * j);
    float2 gf = *(const float2*)(gates + wv * 516 + 128 + 2 * j);
    float2 gg = *(const float2*)(gates + wv * 516 + 256 + 2 * j);
    float2 go = *(const float2*)(gates + wv * 516 + 384 + 2 * j);
    float2 wi0 = *(const float2*)(wih_s + 2 * j);
    float2 wi1 = *(const float2*)(wih_s + 128 + 2 * j);
    float2 wi2 = *(const float2*)(wih_s + 256 + 2 * j);
    float2 wi3 = *(const float2*)(wih_s + 384 + 2 * j);
    float i0 = fast_sig(gi.x + ytil * wi0.x);
    float i1 = fast_sig(gi.y + ytil * wi0.y);
    float f0 = fast_sig(gf.x + ytil * wi1.x);
    float f1 = fast_sig(gf.y + ytil * wi1.y);
    float g0 = fast_tanh(gg.x + ytil * wi2.x);
    float g1 = fast_tanh(gg.y + ytil * wi2.y);
    float o0 = fast_sig(go.x + ytil * wi3.x);
    float o1 = fast_sig(go.y + ytil * wi3.y);
    s0 = f0 * s0 + i0 * g0;
    s1 = f1 * s1 + i1 * g1;
    float d0 = o0 * fast_tanh(s0);
    float d1 = o1 * fast_tanh(s1);
    cat_u[wv * 132 + j] = pack2bf(d0, d1);
    cat_u[wv * 132 + 64 + j] = pack2bf(s0, s1);
    __syncthreads();
  }

  // ---- epilogue: d_64 * Wdec block 64, write d_fin ----
  if (wv >= 8) {
    const int w8 = wv - 8;
#pragma unroll
    for (int kk = 0; kk < 4; ++kk) {
      s16x8 a = *(const s16x8*)(cat_u + arow + kk * 16);
      s16x8 bf = *(const s16x8*)(WdecP + ((((64 * 4 + kk) * 8 + w8) * 64 + lane) * 8));
      dfacc = MFMA16(a, bf, dfacc);
    }
#pragma unroll
    for (int r = 0; r < 4; ++r)
      cat2[(crow + r) * 256 + w8 * 16 + ccol] = dfacc[r];
  }
  beta_s[wv * 64 + lane] = beta_sv;
  __syncthreads();

  // ---- c_T and final head (per wave) ----
  float c0 = 0.f, c1v = 0.f;
#pragma unroll 2
  for (int it = 0; it < 16; ++it) {
    float4 bv = *(const float4*)(beta_s + wv * 64 + it * 4);
    float2 e0 = *(const float2*)(enc + ((size_t)b * 64 + it * 4 + 0) * 128 + 2 * j);
    float2 e1 = *(const float2*)(enc + ((size_t)b * 64 + it * 4 + 1) * 128 + 2 * j);
    float2 e2 = *(const float2*)(enc + ((size_t)b * 64 + it * 4 + 2) * 128 + 2 * j);
    float2 e3 = *(const float2*)(enc + ((size_t)b * 64 + it * 4 + 3) * 128 + 2 * j);
    c0 = fmaf(bv.x, e0.x, c0); c1v = fmaf(bv.x, e0.y, c1v);
    c0 = fmaf(bv.y, e1.x, c0); c1v = fmaf(bv.y, e1.y, c1v);
    c0 = fmaf(bv.z, e2.x, c0); c1v = fmaf(bv.z, e2.y, c1v);
    c0 = fmaf(bv.w, e3.x, c0); c1v = fmaf(bv.w, e3.y, c1v);
  }
  *(float2*)(cat2 + wv * 256 + 128 + 2 * j) = make_float2(c0, c1v);

  float2 hb = *(const float2*)(W_y_b + 2 * j);
  float h0 = hb.x, h1 = hb.y;
  __syncthreads();
#pragma unroll 4
  for (int it = 0; it < 64; ++it) {
    float4 cv = *(const float4*)(cat2 + wv * 256 + it * 4);
    u32 w0 = WyP2[(it * 4 + 0) * 64 + j];
    u32 w1 = WyP2[(it * 4 + 1) * 64 + j];
    u32 w2 = WyP2[(it * 4 + 2) * 64 + j];
    u32 w3 = WyP2[(it * 4 + 3) * 64 + j];
    h2 p0 = as_h2(w0), p1 = as_h2(w1), p2 = as_h2(w2), p3 = as_h2(w3);
    h0 = fmaf(cv.x, (float)p0.x, h0); h1 = fmaf(cv.x, (float)p0.y, h1);
    h0 = fmaf(cv.y, (float)p1.x, h0); h1 = fmaf(cv.y, (float)p1.y, h1);
    h0 = fmaf(cv.z, (float)p2.x, h0); h1 = fmaf(cv.z, (float)p2.y, h1);
    h0 = fmaf(cv.w, (float)p3.x, h0); h1 = fmaf(cv.w, (float)p3.y, h1);
  }
  float2 vy = *(const float2*)(v_y_w + 2 * j);
  float r = h0 * vy.x + h1 * vy.y;
#pragma unroll
  for (int off = 32; off; off >>= 1) r += __shfl_xor(r, off, 64);
  if (lane == 0) out[b] = r + v_y_b[0];
}

extern "C" void kernel_launch(void* const* d_in, const int* in_sizes, int n_in,
                              void* d_out, int out_size, void* d_ws, size_t ws_size,
                              hipStream_t stream) {
  const float* enc = (const float*)d_in[0];
  const float* y = (const float*)d_in[1];
  const float* W_d_w = (const float*)d_in[2];
  const float* W_d_b = (const float*)d_in[3];
  const float* U_d_w = (const float*)d_in[4];
  const float* v_d_w = (const float*)d_in[5];
  const float* w_tilda_w = (const float*)d_in[6];
  const float* w_tilda_b = (const float*)d_in[7];
  const float* W_ih = (const float*)d_in[8];
  const float* b_ih = (const float*)d_in[9];
  const float* W_hh = (const float*)d_in[10];
  const float* b_hh = (const float*)d_in[11];
  const float* W_dec_w = (const float*)d_in[12];
  const float* W_dec_b = (const float*)d_in[13];
  const float* W_y_w = (const float*)d_in[14];
  const float* W_y_b = (const float*)d_in[15];
  const float* v_y_w = (const float*)d_in[16];
  const float* v_y_b = (const float*)d_in[17];

  char* ws = (char*)d_ws;
  short* WdP = (short*)(ws + 0);
  short* WhhP = (short*)(ws + 65536);
  short* WdecP = (short*)(ws + 196608);
  u32* UdP = (u32*)(ws + 2326528);
  u32* wtP = (u32*)(ws + 2359296);
  u32* WyP2 = (u32*)(ws + 2359552);

  pack_weights<<<512, 256, 0, stream>>>(W_d_w, W_hh, W_dec_w, W_y_w, U_d_w,
                                        w_tilda_w, WdP, WhhP, WdecP, UdP, wtP, WyP2);
  fused_main<<<4096 / NB, NTH, LDS_BYTES, stream>>>(
      enc, y, W_d_b, v_d_w, w_tilda_w, w_tilda_b, W_ih, b_ih, b_hh, W_dec_b,
      W_y_b, v_y_w, v_y_b, WdP, WhhP, WdecP, (const uint4*)UdP, wtP, WyP2,
      (float*)d_out);
}